// Round 4
// baseline (342.873 us; speedup 1.0000x reference)
//
#include <hip/hip_runtime.h>

#define N_NODES 100000
#define N_EDGES 1600000
#define D 64

// ---------------- bf16 helpers (raw ushort, RNE) ----------------
__device__ __forceinline__ float bf2f(unsigned short u) {
    return __uint_as_float(((unsigned int)u) << 16);
}
__device__ __forceinline__ unsigned short f2bf(float f) {
    unsigned int i = __float_as_uint(f);
    i += 0x7FFFu + ((i >> 16) & 1u);   // round-to-nearest-even
    return (unsigned short)(i >> 16);
}

// ---------------- CSR build ----------------

__global__ void zero_cnt(int* __restrict__ cnt) {
    int i = blockIdx.x * 256 + threadIdx.x;
    if (i < N_NODES) cnt[i] = 0;
}

// rank[e] = arrival index of edge e at its destination (the ONLY atomic pass)
__global__ void count_rank(const int* __restrict__ col, int* __restrict__ cnt,
                           int* __restrict__ rank) {
    int e = blockIdx.x * 256 + threadIdx.x;
    if (e < N_EDGES) rank[e] = atomicAdd(&cnt[col[e]], 1);
}

// exclusive scan of cnt -> base (3 kernels)
__global__ void scan1(const int* __restrict__ cnt, int* __restrict__ base,
                      int* __restrict__ bsum) {
    __shared__ int s[256];
    int tid = threadIdx.x;
    int i = blockIdx.x * 256 + tid;
    int v = (i < N_NODES) ? cnt[i] : 0;
    s[tid] = v;
    __syncthreads();
    for (int o = 1; o < 256; o <<= 1) {
        int t = (tid >= o) ? s[tid - o] : 0;
        __syncthreads();
        s[tid] += t;
        __syncthreads();
    }
    if (i < N_NODES) base[i] = s[tid] - v;   // exclusive
    if (tid == 255) bsum[blockIdx.x] = s[255];
}

__global__ void scan2(int* __restrict__ bsum, int* __restrict__ base, int nblocks) {
    __shared__ int s[512];
    int tid = threadIdx.x;
    int v = (tid < nblocks) ? bsum[tid] : 0;
    s[tid] = v;
    __syncthreads();
    for (int o = 1; o < 512; o <<= 1) {
        int t = (tid >= o) ? s[tid - o] : 0;
        __syncthreads();
        s[tid] += t;
        __syncthreads();
    }
    if (tid < nblocks) bsum[tid] = s[tid] - v;  // exclusive block offsets
    if (tid == 0) base[N_NODES] = N_EDGES;
}

__global__ void scan3(int* __restrict__ base, const int* __restrict__ bsum) {
    int i = blockIdx.x * 256 + threadIdx.x;
    if (i < N_NODES) base[i] += bsum[blockIdx.x];
}

// epack[base[col]+rank] = {src, raw_weight}  — no atomics
__global__ void scatter_sw(const int* __restrict__ row, const int* __restrict__ col,
                           const float* __restrict__ w, const int* __restrict__ rank,
                           const int* __restrict__ base, int2* __restrict__ epack) {
    int e = blockIdx.x * 256 + threadIdx.x;
    if (e >= N_EDGES) return;
    int c = col[e];
    int pos = base[c] + rank[e];
    int2 p;
    p.x = row[e];
    p.y = __float_as_int(w[e]);
    epack[pos] = p;
}

// dinv[i] = rsqrt(1 + sum of incoming weights) — gather over CSR, no atomics
__global__ void deg_dinv(const int2* __restrict__ epack, const int* __restrict__ base,
                         float* __restrict__ dinv) {
    int i = blockIdx.x * 256 + threadIdx.x;
    if (i >= N_NODES) return;
    float s = 1.0f;  // self-loop weight
    int en = base[i + 1];
    for (int k = base[i]; k < en; ++k) s += __int_as_float(epack[k].y);
    dinv[i] = rsqrtf(s);
}

// ---------------- x (f32) -> xb (bf16) ----------------
__global__ void to_bf16(const float4* __restrict__ in4, ushort4* __restrict__ out4) {
    int gid = blockIdx.x * 256 + threadIdx.x;
    if (gid >= N_NODES * (D / 4)) return;
    float4 v = in4[gid];
    ushort4 o;
    o.x = f2bf(v.x);
    o.y = f2bf(v.y);
    o.z = f2bf(v.z);
    o.w = f2bf(v.w);
    out4[gid] = o;
}

// ---------------- fused layer: out = relu( agg(xb) @ W + b ) ----------------
// agg(x)[i] = dinv[i] * ( dinv[i]*x[i] + sum_e dinv[src]*w * x[src] )
// One wave per node (lane = channel). Gathered operand is bf16 (128B/line per edge);
// accumulate + GEMM in f32. LAST layer writes f32 d_out, else bf16 hb.
template <bool LAST>
__global__ __launch_bounds__(256, 4)
void gcn_layer(const unsigned short* __restrict__ xb, const float* __restrict__ W,
               const float* __restrict__ b, const float* __restrict__ dinv,
               const int2* __restrict__ epack, const int* __restrict__ base,
               unsigned short* __restrict__ hb_out, float* __restrict__ f_out) {
    __shared__ float Ws[D * D];
    __shared__ float xs[4][D];
    int t = threadIdx.x;
    for (int i = t; i < D * D; i += 256) Ws[i] = W[i];
    int ty = t >> 6;
    int d  = t & 63;
    int node = blockIdx.x * 4 + ty;        // N_NODES % 4 == 0
    float s   = dinv[node];
    float acc = s * bf2f(xb[node * D + d]);          // self term
#pragma unroll 4
    for (int k = base[node], en = base[node + 1]; k < en; ++k) {
        int2 p = epack[k];                            // 8B broadcast
        float nv = dinv[p.x] * __int_as_float(p.y);   // 4B broadcast (L2-resident)
        acc = fmaf(nv, bf2f(xb[p.x * D + d]), acc);   // 128B coalesced gather
    }
    xs[ty][d] = s * acc;
    __syncthreads();
    float y = b[d];
#pragma unroll
    for (int k = 0; k < D; ++k) y = fmaf(xs[ty][k], Ws[k * D + d], y);
    y = fmaxf(y, 0.0f);
    if (LAST) f_out[node * D + d] = y;
    else      hb_out[node * D + d] = f2bf(y);
}

extern "C" void kernel_launch(void* const* d_in, const int* in_sizes, int n_in,
                              void* d_out, int out_size, void* d_ws, size_t ws_size,
                              hipStream_t stream) {
    const float* x       = (const float*)d_in[0];
    const int*   adj     = (const int*)d_in[1];    // [2][E]
    const float* adj_wts = (const float*)d_in[2];
    const float* W1      = (const float*)d_in[3];
    const float* b1      = (const float*)d_in[4];
    const float* W2      = (const float*)d_in[5];
    const float* b2      = (const float*)d_in[6];
    float* out = (float*)d_out;

    const int* row = adj;
    const int* col = adj + N_EDGES;

    // workspace layout (N_NODES*4 = 400000 B keeps 16B alignment throughout)
    int*   cnt   = (int*)d_ws;                      // N
    int*   rank  = cnt + N_NODES;                   // E
    int*   base  = rank + N_EDGES;                  // N+1 (+pad)
    int*   bsum  = base + N_NODES + 4;              // 512
    float* dinv  = (float*)(bsum + 512);            // N
    int2*  epack = (int2*)(dinv + N_NODES);         // E int2 (12.8 MB)
    unsigned short* xb = (unsigned short*)(epack + N_EDGES);   // N*D bf16 (12.8 MB)
    unsigned short* hb = xb + (size_t)N_NODES * D;             // N*D bf16 (12.8 MB)

    const int nblk_n  = (N_NODES + 255) / 256;      // 391
    const int nblk_e  = (N_EDGES + 255) / 256;      // 6250
    const int nblk_g  = N_NODES / 4;                // 25000
    const int nblk_c  = (N_NODES * 16 + 255) / 256; // convert: N*D/4 float4s

    // ---- CSR build (one atomic per edge) ----
    zero_cnt<<<nblk_n, 256, 0, stream>>>(cnt);
    count_rank<<<nblk_e, 256, 0, stream>>>(col, cnt, rank);
    scan1<<<nblk_n, 256, 0, stream>>>(cnt, base, bsum);
    scan2<<<1, 512, 0, stream>>>(bsum, base, nblk_n);
    scan3<<<nblk_n, 256, 0, stream>>>(base, bsum);
    scatter_sw<<<nblk_e, 256, 0, stream>>>(row, col, adj_wts, rank, base, epack);
    deg_dinv<<<nblk_n, 256, 0, stream>>>(epack, base, dinv);

    // ---- x -> bf16 ----
    to_bf16<<<nblk_c, 256, 0, stream>>>((const float4*)x, (ushort4*)xb);

    // ---- fused layers (bf16 gather, f32 math) ----
    gcn_layer<false><<<nblk_g, 256, 0, stream>>>(xb, W1, b1, dinv, epack, base, hb, nullptr);
    gcn_layer<true ><<<nblk_g, 256, 0, stream>>>(hb, W2, b2, dinv, epack, base, nullptr, out);
}